// Round 17
// baseline (1102.754 us; speedup 1.0000x reference)
//
#include <hip/hip_runtime.h>
#include <math.h>

// Problem constants
constexpr int Bb = 64;    // batch
constexpr int Pp = 400;   // passage len
constexpr int Qq = 50;    // question len
constexpr int Ee = 300;   // embed dim
constexpr int Hh = 256;   // hidden
constexpr int H3 = 768;   // 3*H
constexpr int Dd = 512;   // 2*H

#define NEGC (-10000000.0f)
#define LOGTINY (-103.278929903f)   // log(float32(1e-45)) = log(2^-149)

typedef _Float16 h2 __attribute__((ext_vector_type(2)));
typedef _Float16 f16x8 __attribute__((ext_vector_type(8)));
typedef float f32x4 __attribute__((ext_vector_type(4)));

__device__ __forceinline__ float allred(float v){
  #pragma unroll
  for (int off = 1; off < 64; off <<= 1) v += __shfl_xor(v, off);
  return v;
}
__device__ __forceinline__ float allmax(float v){
  #pragma unroll
  for (int off = 1; off < 64; off <<= 1) v = fmaxf(v, __shfl_xor(v, off));
  return v;
}
__device__ __forceinline__ float sigm(float x){ return 1.f / (1.f + expf(-x)); }

__device__ __forceinline__ float dot2f(unsigned a, unsigned b, float c){
#if __has_builtin(__builtin_amdgcn_fdot2)
  return __builtin_amdgcn_fdot2(__builtin_bit_cast(h2, a), __builtin_bit_cast(h2, b), c, false);
#else
  float r = c;
  asm("v_dot2_f32_f16 %0, %1, %2, %0" : "+v"(r) : "v"(a), "v"(b));
  return r;
#endif
}

#define U4C(v,c) ((c)==0?(v).x:((c)==1?(v).y:((c)==2?(v).z:(v).w)))
#define PIN4(v) asm volatile("" : "+v"((v).x), "+v"((v).y), "+v"((v).z), "+v"((v).w));

// ---------------------------------------------------------------------------
// gather_a: per used (b,t) position, copy emb[tok] fp32 -> fp16 row [320]
// ---------------------------------------------------------------------------
__global__ __launch_bounds__(256) void gather_a(const int* __restrict__ ptok,
                                                const int* __restrict__ qtok,
                                                const float* __restrict__ emb,
                                                _Float16* __restrict__ Agp,
                                                _Float16* __restrict__ Agq){
  int idx = blockIdx.x * 256 + threadIdx.x;   // chunk id
  if (idx >= (25600 + 3200) * 40) return;
  int ck = idx % 40;
  int row = idx / 40;
  int tokv; _Float16* dst;
  if (row < 25600){ tokv = ptok[row]; dst = Agp + (size_t)row * 320; }
  else { int r = row - 25600; tokv = qtok[r]; dst = Agq + (size_t)r * 320; }
  int c = ck * 8;
  const float* src = emb + (size_t)tokv * Ee;
  f16x8 v;
  #pragma unroll
  for (int i = 0; i < 8; ++i) v[i] = (c + i < Ee) ? (_Float16)src[c + i] : (_Float16)0.f;
  *(f16x8*)(dst + c) = v;
}

// ---------------------------------------------------------------------------
// prep_wih16: Wih fp32 [g][d][768][300] -> fp16 [g][d][768][320] padded
// ---------------------------------------------------------------------------
__global__ __launch_bounds__(256) void prep_wih16(const float* __restrict__ pW,
                                                  const float* __restrict__ qW,
                                                  _Float16* __restrict__ wih16){
  int idx = blockIdx.x * 256 + threadIdx.x;   // pair id: 2*2*768*160
  if (idx >= 2 * 2 * 768 * 160) return;
  int col2 = idx % 160;
  int r = idx / 160;           // g*1536 + d*768 + h
  int g = r / 1536;
  int dh = r % 1536;
  int c = col2 * 2;
  const float* W = g ? qW : pW;
  float2 v = make_float2(0.f, 0.f);
  if (c < Ee) v = *(const float2*)(W + (size_t)dh * Ee + c);
  h2 o = { (_Float16)v.x, (_Float16)v.y };
  *(h2*)(wih16 + (size_t)r * 320 + c) = o;
}

// ---------------------------------------------------------------------------
// prep_w16 for 1024-thread quarter-split 3-tier GRU (r16 layout, unchanged).
// ---------------------------------------------------------------------------
__global__ __launch_bounds__(256) void prep_w16(const float* __restrict__ pW,
                                                const float* __restrict__ qW,
                                                unsigned* __restrict__ w16){
  int idx = blockIdx.x * 256 + threadIdx.x;   // u32 slot id (393216 total)
  if (idx >= 393216) return;
  int c = idx & 3;
  int t = (idx >> 2) & 1023;
  int B = idx >> 12;            // 0..95
  int gd, g, ql;
  if (B < 28){
    gd = B / 7; int rb = B % 7;
    ql = rb / 3; g = rb % 3;
  } else if (B < 64){
    int lb0 = B - 28; gd = lb0 / 9; int lb = lb0 % 9;
    if (lb < 2){ ql = 2; g = lb + 1; }
    else if (lb < 8){ int v = lb - 2; ql = 3 + v / 3; g = v % 3; }
    else { ql = 5; g = 0; }
  } else {
    int sb0 = B - 64; gd = sb0 / 8; int sb = sb0 % 8;
    if (sb < 2){ ql = 5; g = sb + 1; }
    else { int v = sb - 2; ql = 6 + v / 3; g = v % 3; }
  }
  int j = t & 255, qq = t >> 8;
  int p = qq * 32 + ql * 4 + c;
  int row = g * 256 + j;
  int d = gd & 1, kind = gd >> 1;
  const float* W = kind ? qW : pW;
  const float* src = W + ((size_t)d * H3 + row) * Hh + 2 * p;
  _Float16 a = (_Float16)src[0], bb = (_Float16)src[1];
  unsigned short ua, ub;
  __builtin_memcpy(&ua, &a, 2); __builtin_memcpy(&ub, &bb, 2);
  w16[idx] = (unsigned)ua | ((unsigned)ub << 16);
}

// ---------------------------------------------------------------------------
// xproj via MFMA, all-fp16 inputs, gathered A rows (r15, unchanged)
// ---------------------------------------------------------------------------
__global__ __launch_bounds__(512) void xproj_mfma(const _Float16* __restrict__ Ag,
                                                  const _Float16* __restrict__ wih16,
                                                  const float* __restrict__ bih,
                                                  _Float16* __restrict__ xp, int T){
  __shared__ __align__(16) _Float16 Af[128][72];
  __shared__ __align__(16) _Float16 Bf[128][72];
  int tid = threadIdx.x;
  int m0 = blockIdx.y * 128;
  int nt = blockIdx.x;                 // 0..11
  int d = nt / 6, h0 = (nt % 6) * 128;
  int wid = tid >> 6, lane = tid & 63;
  int wr = wid >> 2, wc = wid & 3;

  int r0 = tid >> 3;                    // 0..63
  int r1 = (tid + 512) >> 3;            // 64..127
  int cc = (tid & 7) * 8;
  const _Float16* eA0 = Ag + (size_t)(m0 + r0) * 320;
  const _Float16* eA1 = Ag + (size_t)(m0 + r1) * 320;
  const _Float16* wB0 = wih16 + ((size_t)d * H3 + h0 + r0) * 320;
  const _Float16* wB1 = wih16 + ((size_t)d * H3 + h0 + r1) * 320;

  f32x4 acc[4][2] = {};

  for (int k0 = 0; k0 < 320; k0 += 64){
    *(f16x8*)&Af[r0][cc] = *(const f16x8*)(eA0 + k0 + cc);
    *(f16x8*)&Af[r1][cc] = *(const f16x8*)(eA1 + k0 + cc);
    *(f16x8*)&Bf[r0][cc] = *(const f16x8*)(wB0 + k0 + cc);
    *(f16x8*)&Bf[r1][cc] = *(const f16x8*)(wB1 + k0 + cc);
    __syncthreads();
    #pragma unroll
    for (int kc = 0; kc < 2; ++kc){
      int kb = kc * 32 + (lane >> 4) * 8;
      f16x8 af[4], bf[2];
      #pragma unroll
      for (int i = 0; i < 4; ++i) af[i] = *(const f16x8*)&Af[wr * 64 + i * 16 + (lane & 15)][kb];
      #pragma unroll
      for (int jn = 0; jn < 2; ++jn) bf[jn] = *(const f16x8*)&Bf[wc * 32 + jn * 16 + (lane & 15)][kb];
      #pragma unroll
      for (int i = 0; i < 4; ++i)
        #pragma unroll
        for (int jn = 0; jn < 2; ++jn)
          acc[i][jn] = __builtin_amdgcn_mfma_f32_16x16x32_f16(af[i], bf[jn], acc[i][jn], 0, 0, 0);
    }
    __syncthreads();
  }

  #pragma unroll
  for (int jn = 0; jn < 2; ++jn){
    int h = h0 + wc * 32 + jn * 16 + (lane & 15);
    float bv = bih[d * H3 + h];
    #pragma unroll
    for (int i = 0; i < 4; ++i){
      #pragma unroll
      for (int r = 0; r < 4; ++r){
        int m = m0 + wr * 64 + i * 16 + (lane >> 4) * 4 + r;
        int bI = m / T, tI = m - bI * T;
        xp[(((size_t)d * Bb + bI) * T + tI) * H3 + h] = (_Float16)(acc[i][jn][r] + bv);
      }
    }
  }
}

// ---------------------------------------------------------------------------
// 3-tier GRU, 1024 threads (r16 structure) + CROSS-STEP S-PREFETCH:
// S-tier weights are h-independent, so each group is issued for step s+1
// immediately after its step-s consume -> every S load has ~1 full step
// (~3700 cyc) of latency cover crossing the barriers, instead of the
// same-step 300-1500 cyc that r12-r16 evidence says was the exposed stall.
// asm pins after each issue stop LLVM CSE/hoisting the loop-invariant loads.
// ---------------------------------------------------------------------------
__global__ __launch_bounds__(1024)
void gru_kernel(const int* __restrict__ ptok,
                const int* __restrict__ qtok,
                const _Float16* __restrict__ xpp,
                const _Float16* __restrict__ xpq,
                const unsigned* __restrict__ w16,
                const float* __restrict__ pbhh,
                const float* __restrict__ qbhh,
                float* __restrict__ Hp,
                float* __restrict__ Hq){
  int wg = blockIdx.x;
  bool isp = wg < 128;
  int lw = isp ? wg : wg - 128;
  int d = lw & 1, b = lw >> 1;
  int T = isp ? Pp : Qq;
  const int* tok = (isp ? ptok : qtok) + b * T;
  const _Float16* xrow = (isp ? xpp : xpq) + ((size_t)d * Bb + b) * T * H3;
  int gd = (isp ? 0 : 2) + d;
  const float* bhh = (isp ? pbhh : qbhh) + d * H3;
  float* Hout = (isp ? Hp : Hq) + (size_t)b * T * Dd + d * Hh;

  __shared__ __align__(16) uint4 ldsW[9 * 1024];   // 147456 B
  __shared__ float part[3][3][Hh];                 // 9216 B
  __shared__ unsigned hbuf[2][128];                // 1024 B

  int t = threadIdx.x;
  int j = t & 255, qq = t >> 8, lane = t & 63;
  const uint4* u4w = (const uint4*)w16;

  // R tier: 7 blocks -> 28 u32. rb <-> (ql=rb/3, g=rb%3)
  unsigned wrR[28];
  #pragma unroll
  for (int rb = 0; rb < 7; ++rb){
    uint4 v = u4w[((size_t)gd * 7 + rb) * 1024 + t];
    wrR[4 * rb + 0] = v.x; wrR[4 * rb + 1] = v.y; wrR[4 * rb + 2] = v.z; wrR[4 * rb + 3] = v.w;
  }
  #pragma unroll
  for (int i = 0; i < 28; ++i) asm volatile("" : "+v"(wrR[i]));

  // L tier -> LDS (9 blocks for this gd)
  #pragma unroll
  for (int lb = 0; lb < 9; ++lb)
    ldsW[lb * 1024 + t] = u4w[28 * 1024 + ((size_t)gd * 9 + lb) * 1024 + t];
  const uint4* wS = u4w + 64 * 1024 + (size_t)gd * 8 * 1024;

  float bh0 = bhh[j], bh1 = bhh[Hh + j], bh2 = bhh[2 * Hh + j];
  float h_old = 0.f;
  if (t < 128) hbuf[1][t] = 0u;     // step 0 reads buf[1]
  __syncthreads();

  int t0 = d ? (T - 1) : 0;
  float pre0 = 0.f, pre1 = 0.f, pre2 = 0.f;
  if (qq == 0){
    pre0 = (float)xrow[(size_t)t0 * H3 + j];
    pre1 = (float)xrow[(size_t)t0 * H3 + Hh + j];
    pre2 = (float)xrow[(size_t)t0 * H3 + 2 * Hh + j];
  }

  // Prologue: issue all S groups for step 0 (full-latency cover before use).
  uint4 sA0 = wS[0 * 1024 + t], sA1 = wS[1 * 1024 + t];
  uint4 sB0 = wS[2 * 1024 + t], sB1 = wS[3 * 1024 + t], sB2 = wS[4 * 1024 + t];
  uint4 sC0 = wS[5 * 1024 + t], sC1 = wS[6 * 1024 + t], sC2 = wS[7 * 1024 + t];
  PIN4(sA0) PIN4(sA1) PIN4(sB0) PIN4(sB1) PIN4(sB2) PIN4(sC0) PIN4(sC1) PIN4(sC2)

  for (int s = 0; s < T; ++s){
    int tt = d ? (T - 1 - s) : s;
    unsigned vh = hbuf[(s + 1) & 1][qq * 32 + (lane & 31)];
    float a0 = 0.f, a1 = 0.f, a2 = 0.f;

    // R phase: ql0 (rb0-2), ql1 (rb3-5), ql2-g0 (rb6)
    #pragma unroll
    for (int c = 0; c < 4; ++c){
      unsigned hv = (unsigned)__builtin_amdgcn_readlane((int)vh, c);
      a0 = dot2f(wrR[0 + c], hv, a0);
      a1 = dot2f(wrR[4 + c], hv, a1);
      a2 = dot2f(wrR[8 + c], hv, a2);
    }
    #pragma unroll
    for (int c = 0; c < 4; ++c){
      unsigned hv = (unsigned)__builtin_amdgcn_readlane((int)vh, 4 + c);
      a0 = dot2f(wrR[12 + c], hv, a0);
      a1 = dot2f(wrR[16 + c], hv, a1);
      a2 = dot2f(wrR[20 + c], hv, a2);
    }
    #pragma unroll
    for (int c = 0; c < 4; ++c){
      unsigned hv = (unsigned)__builtin_amdgcn_readlane((int)vh, 8 + c);
      a0 = dot2f(wrR[24 + c], hv, a0);
    }

    // L: ql2 g1,g2 (lb0,lb1)
    { uint4 l1 = ldsW[0 * 1024 + t], l2 = ldsW[1 * 1024 + t];
      #pragma unroll
      for (int c = 0; c < 4; ++c){
        unsigned hv = (unsigned)__builtin_amdgcn_readlane((int)vh, 8 + c);
        a1 = dot2f(U4C(l1, c), hv, a1);
        a2 = dot2f(U4C(l2, c), hv, a2);
      } }
    // L: ql3 all (lb2,3,4)
    { uint4 l0 = ldsW[2 * 1024 + t], l1 = ldsW[3 * 1024 + t], l2 = ldsW[4 * 1024 + t];
      #pragma unroll
      for (int c = 0; c < 4; ++c){
        unsigned hv = (unsigned)__builtin_amdgcn_readlane((int)vh, 12 + c);
        a0 = dot2f(U4C(l0, c), hv, a0);
        a1 = dot2f(U4C(l1, c), hv, a1);
        a2 = dot2f(U4C(l2, c), hv, a2);
      } }

    // consume S group A: ql5 g1,g2 ; then re-issue A for step s+1
    #pragma unroll
    for (int c = 0; c < 4; ++c){
      unsigned hv = (unsigned)__builtin_amdgcn_readlane((int)vh, 20 + c);
      a1 = dot2f(U4C(sA0, c), hv, a1);
      a2 = dot2f(U4C(sA1, c), hv, a2);
    }
    sA0 = wS[0 * 1024 + t]; sA1 = wS[1 * 1024 + t];
    PIN4(sA0) PIN4(sA1)

    // L: ql4 all (lb5,6,7)
    { uint4 l0 = ldsW[5 * 1024 + t], l1 = ldsW[6 * 1024 + t], l2 = ldsW[7 * 1024 + t];
      #pragma unroll
      for (int c = 0; c < 4; ++c){
        unsigned hv = (unsigned)__builtin_amdgcn_readlane((int)vh, 16 + c);
        a0 = dot2f(U4C(l0, c), hv, a0);
        a1 = dot2f(U4C(l1, c), hv, a1);
        a2 = dot2f(U4C(l2, c), hv, a2);
      } }
    // L: ql5 g0 (lb8)
    { uint4 l0 = ldsW[8 * 1024 + t];
      #pragma unroll
      for (int c = 0; c < 4; ++c){
        unsigned hv = (unsigned)__builtin_amdgcn_readlane((int)vh, 20 + c);
        a0 = dot2f(U4C(l0, c), hv, a0);
      } }

    // consume S group B: ql6 all ; re-issue for s+1
    #pragma unroll
    for (int c = 0; c < 4; ++c){
      unsigned hv = (unsigned)__builtin_amdgcn_readlane((int)vh, 24 + c);
      a0 = dot2f(U4C(sB0, c), hv, a0);
      a1 = dot2f(U4C(sB1, c), hv, a1);
      a2 = dot2f(U4C(sB2, c), hv, a2);
    }
    sB0 = wS[2 * 1024 + t]; sB1 = wS[3 * 1024 + t]; sB2 = wS[4 * 1024 + t];
    PIN4(sB0) PIN4(sB1) PIN4(sB2)

    // consume S group C: ql7 all ; re-issue for s+1
    #pragma unroll
    for (int c = 0; c < 4; ++c){
      unsigned hv = (unsigned)__builtin_amdgcn_readlane((int)vh, 28 + c);
      a0 = dot2f(U4C(sC0, c), hv, a0);
      a1 = dot2f(U4C(sC1, c), hv, a1);
      a2 = dot2f(U4C(sC2, c), hv, a2);
    }
    sC0 = wS[5 * 1024 + t]; sC1 = wS[6 * 1024 + t]; sC2 = wS[7 * 1024 + t];
    PIN4(sC0) PIN4(sC1) PIN4(sC2)

    if (qq != 0){
      part[qq - 1][0][j] = a0;
      part[qq - 1][1][j] = a1;
      part[qq - 1][2][j] = a2;
    }
    __syncthreads();
    if (qq == 0){
      float xt0 = pre0, xt1 = pre1, xt2 = pre2;
      if (s + 1 < T){
        int tn = d ? (T - 2 - s) : (s + 1);
        pre0 = (float)xrow[(size_t)tn * H3 + j];
        pre1 = (float)xrow[(size_t)tn * H3 + Hh + j];
        pre2 = (float)xrow[(size_t)tn * H3 + 2 * Hh + j];
      }
      float g0 = a0 + part[0][0][j] + part[1][0][j] + part[2][0][j] + bh0;
      float g1 = a1 + part[0][1][j] + part[1][1][j] + part[2][1][j] + bh1;
      float g2 = a2 + part[0][2][j] + part[1][2][j] + part[2][2][j] + bh2;
      float r = sigm(xt0 + g0);
      float z = sigm(xt1 + g1);
      float n = tanhf(xt2 + r * g2);
      float hnew = (1.f - z) * n + z * h_old;
      float m = (tok[tt] != 0) ? 1.f : 0.f;
      float hm = m * hnew + (1.f - m) * h_old;
      h_old = hm;
      ((_Float16*)hbuf[s & 1])[j] = (_Float16)hm;
      Hout[(size_t)tt * Dd + j] = hm * m;
    }
    __syncthreads();
  }
}

// ---------------------------------------------------------------------------
// Attention + logits (unchanged)
// ---------------------------------------------------------------------------
__global__ __launch_bounds__(512) void attn_kernel(const float* __restrict__ Hp,
                                                   const float* __restrict__ Hq,
                                                   const int* __restrict__ ptok,
                                                   const int* __restrict__ qtok,
                                                   const float* __restrict__ start_w,
                                                   const float* __restrict__ sbp,
                                                   const float* __restrict__ end_w,
                                                   const float* __restrict__ ebp,
                                                   float* __restrict__ out){
  extern __shared__ __align__(16) float lds[];
  float* hqs = lds;               // 50*512
  float* s2s = hqs + Qq * Dd;     // 64
  float* qms = s2s + 64;          // 64
  float* scw = qms + 64;          // 8*64
  float* aw  = scw + 512;         // 8*64

  int b = blockIdx.y, pc = blockIdx.x;
  int tid = threadIdx.x, wid = tid >> 6, lane = tid & 63;
  float sb = sbp[0], eb = ebp[0];

  float w1r[8], w2r[8], w3r[8], e1r[8], e2r[8], e3r[8];
  #pragma unroll
  for (int i = 0; i < 8; ++i){
    int c = lane * 8 + i;
    w1r[i] = start_w[c]; w2r[i] = start_w[Dd + c]; w3r[i] = start_w[2 * Dd + c];
    e1r[i] = end_w[c];   e2r[i] = end_w[Dd + c];   e3r[i] = end_w[2 * Dd + c];
  }
  for (int idx = tid; idx < Qq * Dd; idx += 512) hqs[idx] = Hq[(size_t)b * Qq * Dd + idx];
  __syncthreads();

  for (int q = wid; q < Qq; q += 8){
    float part = 0.f;
    const float* hq = hqs + q * Dd + lane * 8;
    #pragma unroll
    for (int i = 0; i < 8; ++i) part += hq[i] * w2r[i];
    part = allred(part);
    if (lane == 0){
      s2s[q] = part;
      qms[q] = (qtok[b * Qq + q] != 0) ? 1.f : 0.f;
    }
  }
  __syncthreads();

  for (int p = pc * 100 + wid; p < pc * 100 + 100; p += 8){
    const float* hprow = Hp + ((size_t)b * Pp + p) * Dd + lane * 8;
    float4 hv0 = *(const float4*)hprow;
    float4 hv1 = *(const float4*)(hprow + 4);
    float hpc[8] = {hv0.x, hv0.y, hv0.z, hv0.w, hv1.x, hv1.y, hv1.z, hv1.w};
    float hw3[8], he3[8];
    float s1 = 0.f, ed = 0.f;
    #pragma unroll
    for (int i = 0; i < 8; ++i){
      hw3[i] = hpc[i] * w3r[i];
      he3[i] = hpc[i] * e3r[i];
      s1 += hpc[i] * w1r[i];
      ed += hpc[i] * e1r[i];
    }
    #pragma unroll
    for (int off = 1; off < 64; off <<= 1){
      s1 += __shfl_xor(s1, off);
      ed += __shfl_xor(ed, off);
    }
    for (int q = 0; q < Qq; ++q){
      const float4* hq4 = (const float4*)(hqs + q * Dd + lane * 8);
      float4 a0 = hq4[0], a1 = hq4[1];
      float dot = hw3[0] * a0.x + hw3[1] * a0.y + hw3[2] * a0.z + hw3[3] * a0.w
                + hw3[4] * a1.x + hw3[5] * a1.y + hw3[6] * a1.z + hw3[7] * a1.w;
      dot = allred(dot);
      if (lane == 0) scw[wid * 64 + q] = (s1 + s2s[q] + dot + sb) * qms[q];
    }
    float v = (lane < Qq) ? scw[wid * 64 + lane] : -1e30f;
    float M = allmax(v);
    float ev = (lane < Qq) ? expf(v - M) : 0.f;
    float S = allred(ev);
    float am = (lane < Qq) ? (ev / S) * qms[lane] : 0.f;
    float Sm = allred(am);
    float af = am / (Sm + 1e-13f);
    if (lane < Qq) aw[wid * 64 + lane] = af;
    float wv[8] = {0.f, 0.f, 0.f, 0.f, 0.f, 0.f, 0.f, 0.f};
    for (int q = 0; q < Qq; ++q){
      float aq = aw[wid * 64 + q];
      const float4* hq4 = (const float4*)(hqs + q * Dd + lane * 8);
      float4 a0 = hq4[0], a1 = hq4[1];
      wv[0] += aq * a0.x; wv[1] += aq * a0.y; wv[2] += aq * a0.z; wv[3] += aq * a0.w;
      wv[4] += aq * a1.x; wv[5] += aq * a1.y; wv[6] += aq * a1.z; wv[7] += aq * a1.w;
    }
    float acc2 = 0.f, acc3 = 0.f, acc4 = 0.f, acc5 = 0.f;
    #pragma unroll
    for (int i = 0; i < 8; ++i){
      acc2 += wv[i] * w2r[i];
      acc3 += hw3[i] * wv[i];
      acc4 += wv[i] * e2r[i];
      acc5 += he3[i] * wv[i];
    }
    #pragma unroll
    for (int off = 1; off < 64; off <<= 1){
      acc2 += __shfl_xor(acc2, off);
      acc3 += __shfl_xor(acc3, off);
      acc4 += __shfl_xor(acc4, off);
      acc5 += __shfl_xor(acc5, off);
    }
    if (lane == 0){
      bool pm = (ptok[b * Pp + p] != 0);
      out[(size_t)b * Pp + p]                   = pm ? (s1 + acc2 + acc3 + sb) : NEGC;
      out[(size_t)Bb * Pp + (size_t)b * Pp + p] = pm ? (ed + acc4 + acc5 + eb) : NEGC;
    }
  }
}

// ---------------------------------------------------------------------------
// log_softmax over p (unchanged)
// ---------------------------------------------------------------------------
__global__ __launch_bounds__(512) void lsm_kernel(const int* __restrict__ ptok,
                                                  float* __restrict__ out){
  int b = blockIdx.x >> 1, sel = blockIdx.x & 1;
  const float* lg = out + (size_t)sel * Bb * Pp + (size_t)b * Pp;
  float* o = out + (size_t)(2 + sel) * Bb * Pp + (size_t)b * Pp;
  int tid = threadIdx.x;
  __shared__ float red1[8];
  __shared__ float red2[8];
  float x = -1e30f;
  if (tid < Pp) x = lg[tid] + ((ptok[b * Pp + tid] != 0) ? 0.f : LOGTINY);
  float m = allmax(x);
  if ((tid & 63) == 0) red1[tid >> 6] = m;
  __syncthreads();
  float M = red1[0];
  #pragma unroll
  for (int i = 1; i < 8; ++i) M = fmaxf(M, red1[i]);
  float e = (tid < Pp) ? expf(x - M) : 0.f;
  float s = allred(e);
  if ((tid & 63) == 0) red2[tid >> 6] = s;
  __syncthreads();
  float S = 0.f;
  #pragma unroll
  for (int i = 0; i < 8; ++i) S += red2[i];
  if (tid < Pp) o[tid] = (x - M) - logf(S);
}

// ---------------------------------------------------------------------------
extern "C" void kernel_launch(void* const* d_in, const int* in_sizes, int n_in,
                              void* d_out, int out_size, void* d_ws, size_t ws_size,
                              hipStream_t stream){
  const int*   passage  = (const int*)d_in[0];
  const int*   question = (const int*)d_in[1];
  const float* emb      = (const float*)d_in[2];
  const float* pW_ih    = (const float*)d_in[3];
  const float* pW_hh    = (const float*)d_in[4];
  const float* pb_ih    = (const float*)d_in[5];
  const float* pb_hh    = (const float*)d_in[6];
  const float* qW_ih    = (const float*)d_in[7];
  const float* qW_hh    = (const float*)d_in[8];
  const float* qb_ih    = (const float*)d_in[9];
  const float* qb_hh    = (const float*)d_in[10];
  const float* start_w  = (const float*)d_in[11];
  const float* start_b  = (const float*)d_in[12];
  const float* end_w    = (const float*)d_in[13];
  const float* end_b    = (const float*)d_in[14];
  float* out = (float*)d_out;

  // workspace layout (float-sized units)
  float*     ws    = (float*)d_ws;
  unsigned*  w16   = (unsigned*)ws;                    //   393216 u32
  _Float16*  wih16 = (_Float16*)(ws + 393216);         //   983040 halfs = 491520 f
  _Float16*  Agp   = (_Float16*)(ws + 884736);         //  8192000 halfs = 4096000 f
  _Float16*  Agq   = (_Float16*)(ws + 4980736);        //  1024000 halfs = 512000 f
  _Float16*  xpp   = (_Float16*)(ws + 5492736);        // 39321600 halfs = 19660800 f
  _Float16*  xpq   = (_Float16*)(ws + 25153536);       //  4915200 halfs = 2457600 f
  float*     Hp    = ws + 27611136;                    // 13107200 f
  float*     Hq    = ws + 40718336;                    //  1638400 f
  // total 42,356,736 floats = 169 MB

  hipLaunchKernelGGL(prep_w16, dim3(1536), dim3(256), 0, stream, pW_hh, qW_hh, w16);
  hipLaunchKernelGGL(gather_a, dim3(4500), dim3(256), 0, stream,
                     passage, question, emb, Agp, Agq);
  hipLaunchKernelGGL(prep_wih16, dim3(1920), dim3(256), 0, stream, pW_ih, qW_ih, wih16);
  hipLaunchKernelGGL(xproj_mfma, dim3(12, 200), dim3(512), 0, stream,
                     Agp, wih16, pb_ih, xpp, Pp);
  hipLaunchKernelGGL(xproj_mfma, dim3(12, 25), dim3(512), 0, stream,
                     Agq, wih16 + (size_t)2 * H3 * 320, qb_ih, xpq, Qq);
  hipLaunchKernelGGL(gru_kernel, dim3(256), dim3(1024), 0, stream,
                     passage, question, xpp, xpq, w16, pb_hh, qb_hh, Hp, Hq);
  size_t attn_lds = (size_t)(Qq * Dd + 64 + 64 + 512 + 512) * sizeof(float);
  hipLaunchKernelGGL(attn_kernel, dim3(4, 64), dim3(512), attn_lds, stream,
                     Hp, Hq, passage, question, start_w, start_b, end_w, end_b, out);
  hipLaunchKernelGGL(lsm_kernel, dim3(128), dim3(512), 0, stream, passage, out);
}

// Round 18
// 892.494 us; speedup vs baseline: 1.2356x; 1.2356x over previous
//
#include <hip/hip_runtime.h>
#include <math.h>

// Problem constants
constexpr int Bb = 64;    // batch
constexpr int Pp = 400;   // passage len
constexpr int Qq = 50;    // question len
constexpr int Ee = 300;   // embed dim
constexpr int Hh = 256;   // hidden
constexpr int H3 = 768;   // 3*H
constexpr int Dd = 512;   // 2*H

#define NEGC (-10000000.0f)
#define LOGTINY (-103.278929903f)   // log(float32(1e-45)) = log(2^-149)

typedef _Float16 h2 __attribute__((ext_vector_type(2)));
typedef _Float16 f16x8 __attribute__((ext_vector_type(8)));
typedef float f32x4 __attribute__((ext_vector_type(4)));

__device__ __forceinline__ float allred(float v){
  #pragma unroll
  for (int off = 1; off < 64; off <<= 1) v += __shfl_xor(v, off);
  return v;
}
__device__ __forceinline__ float allmax(float v){
  #pragma unroll
  for (int off = 1; off < 64; off <<= 1) v = fmaxf(v, __shfl_xor(v, off));
  return v;
}
__device__ __forceinline__ float sigm(float x){ return 1.f / (1.f + expf(-x)); }

__device__ __forceinline__ float dot2f(unsigned a, unsigned b, float c){
#if __has_builtin(__builtin_amdgcn_fdot2)
  return __builtin_amdgcn_fdot2(__builtin_bit_cast(h2, a), __builtin_bit_cast(h2, b), c, false);
#else
  float r = c;
  asm("v_dot2_f32_f16 %0, %1, %2, %0" : "+v"(r) : "v"(a), "v"(b));
  return r;
#endif
}

#define U4C(v,c) ((c)==0?(v).x:((c)==1?(v).y:((c)==2?(v).z:(v).w)))

// ---------------------------------------------------------------------------
// gather_a: per used (b,t) position, copy emb[tok] fp32 -> fp16 row [320]
// ---------------------------------------------------------------------------
__global__ __launch_bounds__(256) void gather_a(const int* __restrict__ ptok,
                                                const int* __restrict__ qtok,
                                                const float* __restrict__ emb,
                                                _Float16* __restrict__ Agp,
                                                _Float16* __restrict__ Agq){
  int idx = blockIdx.x * 256 + threadIdx.x;   // chunk id
  if (idx >= (25600 + 3200) * 40) return;
  int ck = idx % 40;
  int row = idx / 40;
  int tokv; _Float16* dst;
  if (row < 25600){ tokv = ptok[row]; dst = Agp + (size_t)row * 320; }
  else { int r = row - 25600; tokv = qtok[r]; dst = Agq + (size_t)r * 320; }
  int c = ck * 8;
  const float* src = emb + (size_t)tokv * Ee;
  f16x8 v;
  #pragma unroll
  for (int i = 0; i < 8; ++i) v[i] = (c + i < Ee) ? (_Float16)src[c + i] : (_Float16)0.f;
  *(f16x8*)(dst + c) = v;
}

// ---------------------------------------------------------------------------
// prep_wih16: Wih fp32 [g][d][768][300] -> fp16 [g][d][768][320] padded
// ---------------------------------------------------------------------------
__global__ __launch_bounds__(256) void prep_wih16(const float* __restrict__ pW,
                                                  const float* __restrict__ qW,
                                                  _Float16* __restrict__ wih16){
  int idx = blockIdx.x * 256 + threadIdx.x;   // pair id: 2*2*768*160
  if (idx >= 2 * 2 * 768 * 160) return;
  int col2 = idx % 160;
  int r = idx / 160;           // g*1536 + d*768 + h
  int g = r / 1536;
  int dh = r % 1536;
  int c = col2 * 2;
  const float* W = g ? qW : pW;
  float2 v = make_float2(0.f, 0.f);
  if (c < Ee) v = *(const float2*)(W + (size_t)dh * Ee + c);
  h2 o = { (_Float16)v.x, (_Float16)v.y };
  *(h2*)(wih16 + (size_t)r * 320 + c) = o;
}

// ---------------------------------------------------------------------------
// prep_w16 for 1024-thread quarter-split 3-tier GRU (r16 layout, unchanged).
// ---------------------------------------------------------------------------
__global__ __launch_bounds__(256) void prep_w16(const float* __restrict__ pW,
                                                const float* __restrict__ qW,
                                                unsigned* __restrict__ w16){
  int idx = blockIdx.x * 256 + threadIdx.x;   // u32 slot id (393216 total)
  if (idx >= 393216) return;
  int c = idx & 3;
  int t = (idx >> 2) & 1023;
  int B = idx >> 12;            // 0..95
  int gd, g, ql;
  if (B < 28){
    gd = B / 7; int rb = B % 7;
    ql = rb / 3; g = rb % 3;
  } else if (B < 64){
    int lb0 = B - 28; gd = lb0 / 9; int lb = lb0 % 9;
    if (lb < 2){ ql = 2; g = lb + 1; }
    else if (lb < 8){ int v = lb - 2; ql = 3 + v / 3; g = v % 3; }
    else { ql = 5; g = 0; }
  } else {
    int sb0 = B - 64; gd = sb0 / 8; int sb = sb0 % 8;
    if (sb < 2){ ql = 5; g = sb + 1; }
    else { int v = sb - 2; ql = 6 + v / 3; g = v % 3; }
  }
  int j = t & 255, qq = t >> 8;
  int p = qq * 32 + ql * 4 + c;
  int row = g * 256 + j;
  int d = gd & 1, kind = gd >> 1;
  const float* W = kind ? qW : pW;
  const float* src = W + ((size_t)d * H3 + row) * Hh + 2 * p;
  _Float16 a = (_Float16)src[0], bb = (_Float16)src[1];
  unsigned short ua, ub;
  __builtin_memcpy(&ua, &a, 2); __builtin_memcpy(&ub, &bb, 2);
  w16[idx] = (unsigned)ua | ((unsigned)ub << 16);
}

// ---------------------------------------------------------------------------
// xproj via MFMA + all-masked tile early-exit (masked xp is never read:
// masked GRU steps multiply the gates by m=0, and workspace poison is a
// finite fp16, so skipping the write is exact).
// ---------------------------------------------------------------------------
__global__ __launch_bounds__(512) void xproj_mfma(const int* __restrict__ tok,
                                                  const _Float16* __restrict__ Ag,
                                                  const _Float16* __restrict__ wih16,
                                                  const float* __restrict__ bih,
                                                  _Float16* __restrict__ xp, int T){
  __shared__ __align__(16) _Float16 Af[128][72];
  __shared__ __align__(16) _Float16 Bf[128][72];
  __shared__ int anyflag;
  int tid = threadIdx.x;
  int m0 = blockIdx.y * 128;

  if (tid == 0) anyflag = 0;
  __syncthreads();
  if (tid < 128 && tok[m0 + tid] != 0) anyflag = 1;
  __syncthreads();
  if (!anyflag) return;

  int nt = blockIdx.x;                 // 0..11
  int d = nt / 6, h0 = (nt % 6) * 128;
  int wid = tid >> 6, lane = tid & 63;
  int wr = wid >> 2, wc = wid & 3;

  int r0 = tid >> 3;                    // 0..63
  int r1 = (tid + 512) >> 3;            // 64..127
  int cc = (tid & 7) * 8;
  const _Float16* eA0 = Ag + (size_t)(m0 + r0) * 320;
  const _Float16* eA1 = Ag + (size_t)(m0 + r1) * 320;
  const _Float16* wB0 = wih16 + ((size_t)d * H3 + h0 + r0) * 320;
  const _Float16* wB1 = wih16 + ((size_t)d * H3 + h0 + r1) * 320;

  f32x4 acc[4][2] = {};

  for (int k0 = 0; k0 < 320; k0 += 64){
    *(f16x8*)&Af[r0][cc] = *(const f16x8*)(eA0 + k0 + cc);
    *(f16x8*)&Af[r1][cc] = *(const f16x8*)(eA1 + k0 + cc);
    *(f16x8*)&Bf[r0][cc] = *(const f16x8*)(wB0 + k0 + cc);
    *(f16x8*)&Bf[r1][cc] = *(const f16x8*)(wB1 + k0 + cc);
    __syncthreads();
    #pragma unroll
    for (int kc = 0; kc < 2; ++kc){
      int kb = kc * 32 + (lane >> 4) * 8;
      f16x8 af[4], bf[2];
      #pragma unroll
      for (int i = 0; i < 4; ++i) af[i] = *(const f16x8*)&Af[wr * 64 + i * 16 + (lane & 15)][kb];
      #pragma unroll
      for (int jn = 0; jn < 2; ++jn) bf[jn] = *(const f16x8*)&Bf[wc * 32 + jn * 16 + (lane & 15)][kb];
      #pragma unroll
      for (int i = 0; i < 4; ++i)
        #pragma unroll
        for (int jn = 0; jn < 2; ++jn)
          acc[i][jn] = __builtin_amdgcn_mfma_f32_16x16x32_f16(af[i], bf[jn], acc[i][jn], 0, 0, 0);
    }
    __syncthreads();
  }

  #pragma unroll
  for (int jn = 0; jn < 2; ++jn){
    int h = h0 + wc * 32 + jn * 16 + (lane & 15);
    float bv = bih[d * H3 + h];
    #pragma unroll
    for (int i = 0; i < 4; ++i){
      #pragma unroll
      for (int r = 0; r < 4; ++r){
        int m = m0 + wr * 64 + i * 16 + (lane >> 4) * 4 + r;
        int bI = m / T, tI = m - bI * T;
        xp[(((size_t)d * Bb + bI) * T + tI) * H3 + h] = (_Float16)(acc[i][jn][r] + bv);
      }
    }
  }
}

// ---------------------------------------------------------------------------
// 3-tier GRU, 1024 threads (r16 structure) with the h-broadcast moved from
// v_readlane (VALU + SGPR-hazard) to UNIFORM-ADDRESS ds_read_b128 (LDS-pipe
// hardware broadcast, overlaps the VALU dot chain). No readlanes remain in
// the matvec.
// ---------------------------------------------------------------------------
__global__ __launch_bounds__(1024)
void gru_kernel(const int* __restrict__ ptok,
                const int* __restrict__ qtok,
                const _Float16* __restrict__ xpp,
                const _Float16* __restrict__ xpq,
                const unsigned* __restrict__ w16,
                const float* __restrict__ pbhh,
                const float* __restrict__ qbhh,
                float* __restrict__ Hp,
                float* __restrict__ Hq){
  int wg = blockIdx.x;
  bool isp = wg < 128;
  int lw = isp ? wg : wg - 128;
  int d = lw & 1, b = lw >> 1;
  int T = isp ? Pp : Qq;
  const int* tok = (isp ? ptok : qtok) + b * T;
  const _Float16* xrow = (isp ? xpp : xpq) + ((size_t)d * Bb + b) * T * H3;
  int gd = (isp ? 0 : 2) + d;
  const float* bhh = (isp ? pbhh : qbhh) + d * H3;
  float* Hout = (isp ? Hp : Hq) + (size_t)b * T * Dd + d * Hh;

  __shared__ __align__(16) uint4 ldsW[9 * 1024];   // 147456 B
  __shared__ float part[3][3][Hh];                 // 9216 B
  __shared__ __align__(16) unsigned hbuf[2][128];  // 1024 B

  int t = threadIdx.x;
  int j = t & 255, qq = t >> 8;
  const uint4* u4w = (const uint4*)w16;

  // R tier: 7 blocks -> 28 u32. rb <-> (ql=rb/3, g=rb%3)
  unsigned wrR[28];
  #pragma unroll
  for (int rb = 0; rb < 7; ++rb){
    uint4 v = u4w[((size_t)gd * 7 + rb) * 1024 + t];
    wrR[4 * rb + 0] = v.x; wrR[4 * rb + 1] = v.y; wrR[4 * rb + 2] = v.z; wrR[4 * rb + 3] = v.w;
  }
  #pragma unroll
  for (int i = 0; i < 28; ++i) asm volatile("" : "+v"(wrR[i]));

  // L tier -> LDS (9 blocks for this gd)
  #pragma unroll
  for (int lb = 0; lb < 9; ++lb)
    ldsW[lb * 1024 + t] = u4w[28 * 1024 + ((size_t)gd * 9 + lb) * 1024 + t];
  const uint4* wS = u4w + 64 * 1024 + (size_t)gd * 8 * 1024;

  float bh0 = bhh[j], bh1 = bhh[Hh + j], bh2 = bhh[2 * Hh + j];
  float h_old = 0.f;
  if (t < 128) hbuf[1][t] = 0u;     // step 0 reads buf[1]
  __syncthreads();

  int t0 = d ? (T - 1) : 0;
  float pre0 = 0.f, pre1 = 0.f, pre2 = 0.f;
  if (qq == 0){
    pre0 = (float)xrow[(size_t)t0 * H3 + j];
    pre1 = (float)xrow[(size_t)t0 * H3 + Hh + j];
    pre2 = (float)xrow[(size_t)t0 * H3 + 2 * Hh + j];
  }

  for (int s = 0; s < T; ++s){
    int tt = d ? (T - 1 - s) : s;
    // uniform base for this quarter's 32 h-pairs (hardware broadcast reads)
    const uint4* hb4 = (const uint4*)&hbuf[(s + 1) & 1][qq * 32];
    float a0 = 0.f, a1 = 0.f, a2 = 0.f;

    // issue S loads for this step (consumed at ql5-7, ~2/3 of loop later)
    uint4 sA0 = wS[0 * 1024 + t], sA1 = wS[1 * 1024 + t];
    uint4 sB0 = wS[2 * 1024 + t], sB1 = wS[3 * 1024 + t], sB2 = wS[4 * 1024 + t];
    uint4 sC0 = wS[5 * 1024 + t], sC1 = wS[6 * 1024 + t], sC2 = wS[7 * 1024 + t];

    // DOT3: one ql-quad for all 3 gates from given weight quads
    #define DOT3(HQ, W0e, W1e, W2e) { _Pragma("unroll") \
      for (int c = 0; c < 4; ++c){ \
        unsigned hv = U4C(HQ, c); \
        a0 = dot2f(U4C(W0e, c), hv, a0); \
        a1 = dot2f(U4C(W1e, c), hv, a1); \
        a2 = dot2f(U4C(W2e, c), hv, a2); } }
    #define DOT1(HQ, W0e, ACC) { _Pragma("unroll") \
      for (int c = 0; c < 4; ++c){ \
        unsigned hv = U4C(HQ, c); \
        ACC = dot2f(U4C(W0e, c), hv, ACC); } }
    #define RQ(i) (*(const uint4*)&wrR[4 * (i)])

    uint4 h0q = hb4[0], h1q = hb4[1];
    DOT3(h0q, RQ(0), RQ(1), RQ(2))       // ql0: R
    DOT3(h1q, RQ(3), RQ(4), RQ(5))       // ql1: R
    uint4 h2q = hb4[2], h3q = hb4[3];
    DOT1(h2q, RQ(6), a0)                 // ql2 g0: R
    { uint4 l1 = ldsW[0 * 1024 + t], l2 = ldsW[1 * 1024 + t];
      DOT1(h2q, l1, a1) DOT1(h2q, l2, a2) }            // ql2 g1,g2: L
    { uint4 l0 = ldsW[2 * 1024 + t], l1 = ldsW[3 * 1024 + t], l2 = ldsW[4 * 1024 + t];
      DOT3(h3q, l0, l1, l2) }                          // ql3: L
    uint4 h4q = hb4[4], h5q = hb4[5];
    { uint4 l0 = ldsW[5 * 1024 + t], l1 = ldsW[6 * 1024 + t], l2 = ldsW[7 * 1024 + t];
      DOT3(h4q, l0, l1, l2) }                          // ql4: L
    { uint4 l0 = ldsW[8 * 1024 + t];
      DOT1(h5q, l0, a0) }                              // ql5 g0: L
    DOT1(h5q, sA0, a1) DOT1(h5q, sA1, a2)              // ql5 g1,g2: S
    uint4 h6q = hb4[6], h7q = hb4[7];
    DOT3(h6q, sB0, sB1, sB2)                           // ql6: S
    DOT3(h7q, sC0, sC1, sC2)                           // ql7: S
    #undef DOT3
    #undef DOT1
    #undef RQ

    if (qq != 0){
      part[qq - 1][0][j] = a0;
      part[qq - 1][1][j] = a1;
      part[qq - 1][2][j] = a2;
    }
    __syncthreads();
    if (qq == 0){
      float xt0 = pre0, xt1 = pre1, xt2 = pre2;
      if (s + 1 < T){
        int tn = d ? (T - 2 - s) : (s + 1);
        pre0 = (float)xrow[(size_t)tn * H3 + j];
        pre1 = (float)xrow[(size_t)tn * H3 + Hh + j];
        pre2 = (float)xrow[(size_t)tn * H3 + 2 * Hh + j];
      }
      float g0 = a0 + part[0][0][j] + part[1][0][j] + part[2][0][j] + bh0;
      float g1 = a1 + part[0][1][j] + part[1][1][j] + part[2][1][j] + bh1;
      float g2 = a2 + part[0][2][j] + part[1][2][j] + part[2][2][j] + bh2;
      float r = sigm(xt0 + g0);
      float z = sigm(xt1 + g1);
      float n = tanhf(xt2 + r * g2);
      float hnew = (1.f - z) * n + z * h_old;
      float m = (tok[tt] != 0) ? 1.f : 0.f;
      float hm = m * hnew + (1.f - m) * h_old;
      h_old = hm;
      ((_Float16*)hbuf[s & 1])[j] = (_Float16)hm;
      Hout[(size_t)tt * Dd + j] = hm * m;
    }
    __syncthreads();
  }
}

// ---------------------------------------------------------------------------
// Attention + logits (unchanged)
// ---------------------------------------------------------------------------
__global__ __launch_bounds__(512) void attn_kernel(const float* __restrict__ Hp,
                                                   const float* __restrict__ Hq,
                                                   const int* __restrict__ ptok,
                                                   const int* __restrict__ qtok,
                                                   const float* __restrict__ start_w,
                                                   const float* __restrict__ sbp,
                                                   const float* __restrict__ end_w,
                                                   const float* __restrict__ ebp,
                                                   float* __restrict__ out){
  extern __shared__ __align__(16) float lds[];
  float* hqs = lds;               // 50*512
  float* s2s = hqs + Qq * Dd;     // 64
  float* qms = s2s + 64;          // 64
  float* scw = qms + 64;          // 8*64
  float* aw  = scw + 512;         // 8*64

  int b = blockIdx.y, pc = blockIdx.x;
  int tid = threadIdx.x, wid = tid >> 6, lane = tid & 63;
  float sb = sbp[0], eb = ebp[0];

  float w1r[8], w2r[8], w3r[8], e1r[8], e2r[8], e3r[8];
  #pragma unroll
  for (int i = 0; i < 8; ++i){
    int c = lane * 8 + i;
    w1r[i] = start_w[c]; w2r[i] = start_w[Dd + c]; w3r[i] = start_w[2 * Dd + c];
    e1r[i] = end_w[c];   e2r[i] = end_w[Dd + c];   e3r[i] = end_w[2 * Dd + c];
  }
  for (int idx = tid; idx < Qq * Dd; idx += 512) hqs[idx] = Hq[(size_t)b * Qq * Dd + idx];
  __syncthreads();

  for (int q = wid; q < Qq; q += 8){
    float part = 0.f;
    const float* hq = hqs + q * Dd + lane * 8;
    #pragma unroll
    for (int i = 0; i < 8; ++i) part += hq[i] * w2r[i];
    part = allred(part);
    if (lane == 0){
      s2s[q] = part;
      qms[q] = (qtok[b * Qq + q] != 0) ? 1.f : 0.f;
    }
  }
  __syncthreads();

  for (int p = pc * 100 + wid; p < pc * 100 + 100; p += 8){
    const float* hprow = Hp + ((size_t)b * Pp + p) * Dd + lane * 8;
    float4 hv0 = *(const float4*)hprow;
    float4 hv1 = *(const float4*)(hprow + 4);
    float hpc[8] = {hv0.x, hv0.y, hv0.z, hv0.w, hv1.x, hv1.y, hv1.z, hv1.w};
    float hw3[8], he3[8];
    float s1 = 0.f, ed = 0.f;
    #pragma unroll
    for (int i = 0; i < 8; ++i){
      hw3[i] = hpc[i] * w3r[i];
      he3[i] = hpc[i] * e3r[i];
      s1 += hpc[i] * w1r[i];
      ed += hpc[i] * e1r[i];
    }
    #pragma unroll
    for (int off = 1; off < 64; off <<= 1){
      s1 += __shfl_xor(s1, off);
      ed += __shfl_xor(ed, off);
    }
    for (int q = 0; q < Qq; ++q){
      const float4* hq4 = (const float4*)(hqs + q * Dd + lane * 8);
      float4 a0 = hq4[0], a1 = hq4[1];
      float dot = hw3[0] * a0.x + hw3[1] * a0.y + hw3[2] * a0.z + hw3[3] * a0.w
                + hw3[4] * a1.x + hw3[5] * a1.y + hw3[6] * a1.z + hw3[7] * a1.w;
      dot = allred(dot);
      if (lane == 0) scw[wid * 64 + q] = (s1 + s2s[q] + dot + sb) * qms[q];
    }
    float v = (lane < Qq) ? scw[wid * 64 + lane] : -1e30f;
    float M = allmax(v);
    float ev = (lane < Qq) ? expf(v - M) : 0.f;
    float S = allred(ev);
    float am = (lane < Qq) ? (ev / S) * qms[lane] : 0.f;
    float Sm = allred(am);
    float af = am / (Sm + 1e-13f);
    if (lane < Qq) aw[wid * 64 + lane] = af;
    float wv[8] = {0.f, 0.f, 0.f, 0.f, 0.f, 0.f, 0.f, 0.f};
    for (int q = 0; q < Qq; ++q){
      float aq = aw[wid * 64 + q];
      const float4* hq4 = (const float4*)(hqs + q * Dd + lane * 8);
      float4 a0 = hq4[0], a1 = hq4[1];
      wv[0] += aq * a0.x; wv[1] += aq * a0.y; wv[2] += aq * a0.z; wv[3] += aq * a0.w;
      wv[4] += aq * a1.x; wv[5] += aq * a1.y; wv[6] += aq * a1.z; wv[7] += aq * a1.w;
    }
    float acc2 = 0.f, acc3 = 0.f, acc4 = 0.f, acc5 = 0.f;
    #pragma unroll
    for (int i = 0; i < 8; ++i){
      acc2 += wv[i] * w2r[i];
      acc3 += hw3[i] * wv[i];
      acc4 += wv[i] * e2r[i];
      acc5 += he3[i] * wv[i];
    }
    #pragma unroll
    for (int off = 1; off < 64; off <<= 1){
      acc2 += __shfl_xor(acc2, off);
      acc3 += __shfl_xor(acc3, off);
      acc4 += __shfl_xor(acc4, off);
      acc5 += __shfl_xor(acc5, off);
    }
    if (lane == 0){
      bool pm = (ptok[b * Pp + p] != 0);
      out[(size_t)b * Pp + p]                   = pm ? (s1 + acc2 + acc3 + sb) : NEGC;
      out[(size_t)Bb * Pp + (size_t)b * Pp + p] = pm ? (ed + acc4 + acc5 + eb) : NEGC;
    }
  }
}

// ---------------------------------------------------------------------------
// log_softmax over p (unchanged)
// ---------------------------------------------------------------------------
__global__ __launch_bounds__(512) void lsm_kernel(const int* __restrict__ ptok,
                                                  float* __restrict__ out){
  int b = blockIdx.x >> 1, sel = blockIdx.x & 1;
  const float* lg = out + (size_t)sel * Bb * Pp + (size_t)b * Pp;
  float* o = out + (size_t)(2 + sel) * Bb * Pp + (size_t)b * Pp;
  int tid = threadIdx.x;
  __shared__ float red1[8];
  __shared__ float red2[8];
  float x = -1e30f;
  if (tid < Pp) x = lg[tid] + ((ptok[b * Pp + tid] != 0) ? 0.f : LOGTINY);
  float m = allmax(x);
  if ((tid & 63) == 0) red1[tid >> 6] = m;
  __syncthreads();
  float M = red1[0];
  #pragma unroll
  for (int i = 1; i < 8; ++i) M = fmaxf(M, red1[i]);
  float e = (tid < Pp) ? expf(x - M) : 0.f;
  float s = allred(e);
  if ((tid & 63) == 0) red2[tid >> 6] = s;
  __syncthreads();
  float S = 0.f;
  #pragma unroll
  for (int i = 0; i < 8; ++i) S += red2[i];
  if (tid < Pp) o[tid] = (x - M) - logf(S);
}

// ---------------------------------------------------------------------------
extern "C" void kernel_launch(void* const* d_in, const int* in_sizes, int n_in,
                              void* d_out, int out_size, void* d_ws, size_t ws_size,
                              hipStream_t stream){
  const int*   passage  = (const int*)d_in[0];
  const int*   question = (const int*)d_in[1];
  const float* emb      = (const float*)d_in[2];
  const float* pW_ih    = (const float*)d_in[3];
  const float* pW_hh    = (const float*)d_in[4];
  const float* pb_ih    = (const float*)d_in[5];
  const float* pb_hh    = (const float*)d_in[6];
  const float* qW_ih    = (const float*)d_in[7];
  const float* qW_hh    = (const float*)d_in[8];
  const float* qb_ih    = (const float*)d_in[9];
  const float* qb_hh    = (const float*)d_in[10];
  const float* start_w  = (const float*)d_in[11];
  const float* start_b  = (const float*)d_in[12];
  const float* end_w    = (const float*)d_in[13];
  const float* end_b    = (const float*)d_in[14];
  float* out = (float*)d_out;

  // workspace layout (float-sized units)
  float*     ws    = (float*)d_ws;
  unsigned*  w16   = (unsigned*)ws;                    //   393216 u32
  _Float16*  wih16 = (_Float16*)(ws + 393216);         //   983040 halfs = 491520 f
  _Float16*  Agp   = (_Float16*)(ws + 884736);         //  8192000 halfs = 4096000 f
  _Float16*  Agq   = (_Float16*)(ws + 4980736);        //  1024000 halfs = 512000 f
  _Float16*  xpp   = (_Float16*)(ws + 5492736);        // 39321600 halfs = 19660800 f
  _Float16*  xpq   = (_Float16*)(ws + 25153536);       //  4915200 halfs = 2457600 f
  float*     Hp    = ws + 27611136;                    // 13107200 f
  float*     Hq    = ws + 40718336;                    //  1638400 f
  // total 42,356,736 floats = 169 MB

  hipLaunchKernelGGL(prep_w16, dim3(1536), dim3(256), 0, stream, pW_hh, qW_hh, w16);
  hipLaunchKernelGGL(gather_a, dim3(4500), dim3(256), 0, stream,
                     passage, question, emb, Agp, Agq);
  hipLaunchKernelGGL(prep_wih16, dim3(1920), dim3(256), 0, stream, pW_ih, qW_ih, wih16);
  hipLaunchKernelGGL(xproj_mfma, dim3(12, 200), dim3(512), 0, stream,
                     passage, Agp, wih16, pb_ih, xpp, Pp);
  hipLaunchKernelGGL(xproj_mfma, dim3(12, 25), dim3(512), 0, stream,
                     question, Agq, wih16 + (size_t)2 * H3 * 320, qb_ih, xpq, Qq);
  hipLaunchKernelGGL(gru_kernel, dim3(256), dim3(1024), 0, stream,
                     passage, question, xpp, xpq, w16, pb_hh, qb_hh, Hp, Hq);
  size_t attn_lds = (size_t)(Qq * Dd + 64 + 64 + 512 + 512) * sizeof(float);
  hipLaunchKernelGGL(attn_kernel, dim3(4, 64), dim3(512), attn_lds, stream,
                     Hp, Hq, passage, question, start_w, start_b, end_w, end_b, out);
  hipLaunchKernelGGL(lsm_kernel, dim3(128), dim3(512), 0, stream, passage, out);
}